// Round 1
// baseline (8631.835 us; speedup 1.0000x reference)
//
#include <hip/hip_runtime.h>
#include <math.h>

#define B_   16
#define N_   2000
#define W_   32
#define F_   5
#define TH_  128
#define M_   (B_*N_)   // 32000
#define SH_  64
#define HEADS_ 4
#define C_   16
#define NPB  32        // nodes per block in GRU kernel

__device__ __forceinline__ float sigmoidf_(float x) { return 1.0f / (1.0f + expf(-x)); }
__device__ __forceinline__ float leaky_(float x)    { return x > 0.0f ? x : 0.2f * x; }

__device__ __forceinline__ unsigned enc_(float f) {
  unsigned u = __float_as_uint(f);
  return (u & 0x80000000u) ? ~u : (u | 0x80000000u);
}
__device__ __forceinline__ float dec_(unsigned u) {
  u = (u & 0x80000000u) ? (u ^ 0x80000000u) : ~u;
  return __uint_as_float(u);
}

// ---------------------------------------------------------------------------
// Fused 2-layer GRU over 32 timesteps + LayerNorm -> temb [M][128]
// h stored unit-major in LDS: hs[128][32] (conflict-free across node lanes)
// ---------------------------------------------------------------------------
__global__ __launch_bounds__(256, 2)
void gru_kernel(const float* __restrict__ x,
                const float* __restrict__ Wih0, const float* __restrict__ Whh0,
                const float* __restrict__ bih0, const float* __restrict__ bhh0,
                const float* __restrict__ Wih1, const float* __restrict__ Whh1,
                const float* __restrict__ bih1, const float* __restrict__ bhh1,
                const float* __restrict__ ln1g, const float* __restrict__ ln1b,
                float* __restrict__ temb)
{
  __shared__ float h0s[TH_][NPB];
  __shared__ float h1s[TH_][NPB];
  __shared__ float xs[NPB][W_ * F_];
  __shared__ float wih0s[3 * TH_ * F_];
  __shared__ float br0[TH_], bz0[TH_], bni0[TH_], bnh0[TH_];
  __shared__ float br1[TH_], bz1[TH_], bni1[TH_], bnh1[TH_];

  const int tid = threadIdx.x;
  const int mbase = blockIdx.x * NPB;

  for (int i = tid; i < NPB * W_ * F_; i += 256)
    ((float*)xs)[i] = x[(size_t)mbase * (W_ * F_) + i];
  for (int i = tid; i < 3 * TH_ * F_; i += 256) wih0s[i] = Wih0[i];
  if (tid < TH_) {
    br0[tid]  = bih0[tid] + bhh0[tid];
    bz0[tid]  = bih0[TH_ + tid] + bhh0[TH_ + tid];
    bni0[tid] = bih0[2 * TH_ + tid];
    bnh0[tid] = bhh0[2 * TH_ + tid];
    br1[tid]  = bih1[tid] + bhh1[tid];
    bz1[tid]  = bih1[TH_ + tid] + bhh1[TH_ + tid];
    bni1[tid] = bih1[2 * TH_ + tid];
    bnh1[tid] = bhh1[2 * TH_ + tid];
  }
  for (int i = tid; i < TH_ * NPB; i += 256) {
    ((float*)h0s)[i] = 0.0f;
    ((float*)h1s)[i] = 0.0f;
  }
  __syncthreads();

  const int jg = tid >> 3;   // 0..31 -> hidden units j0..j0+3
  const int ng = tid & 7;    // 0..7  -> nodes n0..n0+3
  const int j0 = jg * 4, n0 = ng * 4;

  float accr[4][4], accz[4][4], accni[4][4], accnh[4][4];  // [ji][ni]

  for (int t = 0; t < W_; ++t) {
    // ================= layer 0 =================
    float xv[4][F_];
#pragma unroll
    for (int ni = 0; ni < 4; ++ni)
#pragma unroll
      for (int f = 0; f < F_; ++f) xv[ni][f] = xs[n0 + ni][t * F_ + f];

#pragma unroll
    for (int ji = 0; ji < 4; ++ji) {
      const int j = j0 + ji;
      float wr[F_], wz[F_], wn[F_];
#pragma unroll
      for (int f = 0; f < F_; ++f) {
        wr[f] = wih0s[j * F_ + f];
        wz[f] = wih0s[(TH_ + j) * F_ + f];
        wn[f] = wih0s[(2 * TH_ + j) * F_ + f];
      }
      const float cr = br0[j], cz = bz0[j], cni = bni0[j], cnh = bnh0[j];
#pragma unroll
      for (int ni = 0; ni < 4; ++ni) {
        float r = cr, z = cz, vi = cni;
#pragma unroll
        for (int f = 0; f < F_; ++f) {
          r  += xv[ni][f] * wr[f];
          z  += xv[ni][f] * wz[f];
          vi += xv[ni][f] * wn[f];
        }
        accr[ji][ni] = r; accz[ji][ni] = z; accni[ji][ni] = vi; accnh[ji][ni] = cnh;
      }
    }

    for (int k0 = 0; k0 < TH_; k0 += 4) {
      float hv[4][4];  // [kk][ni]
#pragma unroll
      for (int kk = 0; kk < 4; ++kk) {
        float4 t4 = *(const float4*)&h0s[k0 + kk][n0];
        hv[kk][0] = t4.x; hv[kk][1] = t4.y; hv[kk][2] = t4.z; hv[kk][3] = t4.w;
      }
#pragma unroll
      for (int ji = 0; ji < 4; ++ji) {
        const int j = j0 + ji;
        const float4 wr = *(const float4*)&Whh0[(size_t)j * TH_ + k0];
        const float4 wz = *(const float4*)&Whh0[(size_t)(TH_ + j) * TH_ + k0];
        const float4 wn = *(const float4*)&Whh0[(size_t)(2 * TH_ + j) * TH_ + k0];
#pragma unroll
        for (int ni = 0; ni < 4; ++ni) {
          accr[ji][ni]  += hv[0][ni] * wr.x + hv[1][ni] * wr.y + hv[2][ni] * wr.z + hv[3][ni] * wr.w;
          accz[ji][ni]  += hv[0][ni] * wz.x + hv[1][ni] * wz.y + hv[2][ni] * wz.z + hv[3][ni] * wz.w;
          accnh[ji][ni] += hv[0][ni] * wn.x + hv[1][ni] * wn.y + hv[2][ni] * wn.z + hv[3][ni] * wn.w;
        }
      }
    }

    float hnew[4][4];  // [ji][ni]
#pragma unroll
    for (int ji = 0; ji < 4; ++ji)
#pragma unroll
      for (int ni = 0; ni < 4; ++ni) {
        const float hold = h0s[j0 + ji][n0 + ni];
        const float r = sigmoidf_(accr[ji][ni]);
        const float z = sigmoidf_(accz[ji][ni]);
        const float nn = tanhf(accni[ji][ni] + r * accnh[ji][ni]);
        hnew[ji][ni] = (1.0f - z) * nn + z * hold;
      }
    __syncthreads();
#pragma unroll
    for (int ji = 0; ji < 4; ++ji)
      *(float4*)&h0s[j0 + ji][n0] =
          make_float4(hnew[ji][0], hnew[ji][1], hnew[ji][2], hnew[ji][3]);
    __syncthreads();

    // ================= layer 1 =================
#pragma unroll
    for (int ji = 0; ji < 4; ++ji) {
      const int j = j0 + ji;
      const float cr = br1[j], cz = bz1[j], cni = bni1[j], cnh = bnh1[j];
#pragma unroll
      for (int ni = 0; ni < 4; ++ni) {
        accr[ji][ni] = cr; accz[ji][ni] = cz; accni[ji][ni] = cni; accnh[ji][ni] = cnh;
      }
    }

    for (int k0 = 0; k0 < TH_; k0 += 4) {
      float av[4][4], bv[4][4];  // [kk][ni]
#pragma unroll
      for (int kk = 0; kk < 4; ++kk) {
        float4 a4 = *(const float4*)&h0s[k0 + kk][n0];
        float4 b4 = *(const float4*)&h1s[k0 + kk][n0];
        av[kk][0] = a4.x; av[kk][1] = a4.y; av[kk][2] = a4.z; av[kk][3] = a4.w;
        bv[kk][0] = b4.x; bv[kk][1] = b4.y; bv[kk][2] = b4.z; bv[kk][3] = b4.w;
      }
#pragma unroll
      for (int ji = 0; ji < 4; ++ji) {
        const int j = j0 + ji;
        const float4 wri = *(const float4*)&Wih1[(size_t)j * TH_ + k0];
        const float4 wzi = *(const float4*)&Wih1[(size_t)(TH_ + j) * TH_ + k0];
        const float4 wni = *(const float4*)&Wih1[(size_t)(2 * TH_ + j) * TH_ + k0];
        const float4 wrh = *(const float4*)&Whh1[(size_t)j * TH_ + k0];
        const float4 wzh = *(const float4*)&Whh1[(size_t)(TH_ + j) * TH_ + k0];
        const float4 wnh = *(const float4*)&Whh1[(size_t)(2 * TH_ + j) * TH_ + k0];
#pragma unroll
        for (int ni = 0; ni < 4; ++ni) {
          accr[ji][ni]  += av[0][ni] * wri.x + av[1][ni] * wri.y + av[2][ni] * wri.z + av[3][ni] * wri.w;
          accr[ji][ni]  += bv[0][ni] * wrh.x + bv[1][ni] * wrh.y + bv[2][ni] * wrh.z + bv[3][ni] * wrh.w;
          accz[ji][ni]  += av[0][ni] * wzi.x + av[1][ni] * wzi.y + av[2][ni] * wzi.z + av[3][ni] * wzi.w;
          accz[ji][ni]  += bv[0][ni] * wzh.x + bv[1][ni] * wzh.y + bv[2][ni] * wzh.z + bv[3][ni] * wzh.w;
          accni[ji][ni] += av[0][ni] * wni.x + av[1][ni] * wni.y + av[2][ni] * wni.z + av[3][ni] * wni.w;
          accnh[ji][ni] += bv[0][ni] * wnh.x + bv[1][ni] * wnh.y + bv[2][ni] * wnh.z + bv[3][ni] * wnh.w;
        }
      }
    }

#pragma unroll
    for (int ji = 0; ji < 4; ++ji)
#pragma unroll
      for (int ni = 0; ni < 4; ++ni) {
        const float hold = h1s[j0 + ji][n0 + ni];
        const float r = sigmoidf_(accr[ji][ni]);
        const float z = sigmoidf_(accz[ji][ni]);
        const float nn = tanhf(accni[ji][ni] + r * accnh[ji][ni]);
        hnew[ji][ni] = (1.0f - z) * nn + z * hold;
      }
    __syncthreads();
#pragma unroll
    for (int ji = 0; ji < 4; ++ji)
      *(float4*)&h1s[j0 + ji][n0] =
          make_float4(hnew[ji][0], hnew[ji][1], hnew[ji][2], hnew[ji][3]);
    __syncthreads();
  }

  // LayerNorm over 128 units per node -> temb
  if (tid < NPB) {
    const int n = tid;
    float mu = 0.0f;
    for (int j = 0; j < TH_; ++j) mu += h1s[j][n];
    mu *= (1.0f / TH_);
    float var = 0.0f;
    for (int j = 0; j < TH_; ++j) {
      const float d = h1s[j][n] - mu;
      var += d * d;
    }
    var *= (1.0f / TH_);
    const float inv = rsqrtf(var + 1e-5f);
    for (int j = 0; j < TH_; ++j)
      temb[(size_t)(mbase + n) * TH_ + j] = (h1s[j][n] - mu) * inv * ln1g[j] + ln1b[j];
  }
}

// ---------------------------------------------------------------------------
// xp = temb @ gat_W -> [M][64]; a_src/a_dst -> [M][4]
// ---------------------------------------------------------------------------
__global__ __launch_bounds__(256)
void gat_xp_kernel(const float* __restrict__ temb, const float* __restrict__ gatW,
                   const float* __restrict__ attS, const float* __restrict__ attD,
                   float* __restrict__ xp, float* __restrict__ asrc, float* __restrict__ adst)
{
  __shared__ float ts[64][TH_ + 4];
  __shared__ float4 ws4[TH_][16];  // gat_W rows as float4 (64 ch = 16 float4)
  __shared__ float sa[64], sd[64];

  const int tid = threadIdx.x;
  const int mbase = blockIdx.x * 64;

  for (int i = tid; i < 64 * TH_; i += 256) {
    const int n = i >> 7, k = i & 127;
    ts[n][k] = temb[(size_t)mbase * TH_ + i];
  }
  for (int i = tid; i < TH_ * 16; i += 256)
    ((float4*)ws4)[i] = ((const float4*)gatW)[i];
  if (tid < 64) { sa[tid] = attS[tid]; sd[tid] = attD[tid]; }
  __syncthreads();

  const int nl = tid >> 2;  // local node 0..63
  const int q  = tid & 3;   // head 0..3
  float4 acc[4];
#pragma unroll
  for (int i = 0; i < 4; ++i) acc[i] = make_float4(0.f, 0.f, 0.f, 0.f);

  for (int k = 0; k < TH_; ++k) {
    const float tv = ts[nl][k];
#pragma unroll
    for (int c0 = 0; c0 < 4; ++c0) {
      const float4 wv = ws4[k][q * 4 + c0];
      acc[c0].x += tv * wv.x; acc[c0].y += tv * wv.y;
      acc[c0].z += tv * wv.z; acc[c0].w += tv * wv.w;
    }
  }

  float as = 0.0f, ad = 0.0f;
#pragma unroll
  for (int c0 = 0; c0 < 4; ++c0) {
    const int base = q * 16 + c0 * 4;
    as += acc[c0].x * sa[base + 0] + acc[c0].y * sa[base + 1] +
          acc[c0].z * sa[base + 2] + acc[c0].w * sa[base + 3];
    ad += acc[c0].x * sd[base + 0] + acc[c0].y * sd[base + 1] +
          acc[c0].z * sd[base + 2] + acc[c0].w * sd[base + 3];
  }

  const int m = mbase + nl;
  asrc[m * 4 + q] = as;
  adst[m * 4 + q] = ad;
  float4* xpo = (float4*)&xp[(size_t)m * 64 + q * 16];
#pragma unroll
  for (int c0 = 0; c0 < 4; ++c0) xpo[c0] = acc[c0];
}

// ---------------------------------------------------------------------------
__global__ void init_kernel(unsigned* __restrict__ amax, float* __restrict__ den,
                            float* __restrict__ num)
{
  const int i = blockIdx.x * 256 + threadIdx.x;
  if (i < M_ * 4) { amax[i] = 0u; den[i] = 0.0f; }
  if (i < M_ * 64) num[i] = 0.0f;
}

__global__ void edge_amax_kernel(const int* __restrict__ ei, const int EB,
                                 const float* __restrict__ asrc, const float* __restrict__ adst,
                                 unsigned* __restrict__ amax)
{
  const int e = blockIdx.x * 256 + threadIdx.x;
  const int ET = B_ * EB + M_;
  if (e >= ET) return;
  int s, d;
  if (e < B_ * EB) {
    const int b = e / EB, r = e - b * EB, off = b * N_;
    s = ei[r] + off;
    d = ei[EB + r] + off;
  } else {
    s = d = e - B_ * EB;
  }
  const float4 as = *(const float4*)&asrc[s * 4];
  const float4 ad = *(const float4*)&adst[d * 4];
  atomicMax(&amax[d * 4 + 0], enc_(leaky_(as.x + ad.x)));
  atomicMax(&amax[d * 4 + 1], enc_(leaky_(as.y + ad.y)));
  atomicMax(&amax[d * 4 + 2], enc_(leaky_(as.z + ad.z)));
  atomicMax(&amax[d * 4 + 3], enc_(leaky_(as.w + ad.w)));
}

__global__ void edge_sum_kernel(const int* __restrict__ ei, const int EB,
                                const float* __restrict__ asrc, const float* __restrict__ adst,
                                const unsigned* __restrict__ amax, const float* __restrict__ xp,
                                float* __restrict__ den, float* __restrict__ num)
{
  const int e = blockIdx.x * 256 + threadIdx.x;
  const int ET = B_ * EB + M_;
  if (e >= ET) return;
  int s, d;
  if (e < B_ * EB) {
    const int b = e / EB, r = e - b * EB, off = b * N_;
    s = ei[r] + off;
    d = ei[EB + r] + off;
  } else {
    s = d = e - B_ * EB;
  }
  const float4 as = *(const float4*)&asrc[s * 4];
  const float4 ad = *(const float4*)&adst[d * 4];
  float ex[4];
  ex[0] = expf(leaky_(as.x + ad.x) - dec_(amax[d * 4 + 0]));
  ex[1] = expf(leaky_(as.y + ad.y) - dec_(amax[d * 4 + 1]));
  ex[2] = expf(leaky_(as.z + ad.z) - dec_(amax[d * 4 + 2]));
  ex[3] = expf(leaky_(as.w + ad.w) - dec_(amax[d * 4 + 3]));
  unsafeAtomicAdd(&den[d * 4 + 0], ex[0]);
  unsafeAtomicAdd(&den[d * 4 + 1], ex[1]);
  unsafeAtomicAdd(&den[d * 4 + 2], ex[2]);
  unsafeAtomicAdd(&den[d * 4 + 3], ex[3]);

  const float4* xps = (const float4*)&xp[(size_t)s * 64];
  float* nd = &num[(size_t)d * 64];
#pragma unroll
  for (int cq = 0; cq < 16; ++cq) {
    const float4 v = xps[cq];
    const float w = ex[cq >> 2];
    unsafeAtomicAdd(&nd[cq * 4 + 0], w * v.x);
    unsafeAtomicAdd(&nd[cq * 4 + 1], w * v.y);
    unsafeAtomicAdd(&nd[cq * 4 + 2], w * v.z);
    unsafeAtomicAdd(&nd[cq * 4 + 3], w * v.w);
  }
}

// ---------------------------------------------------------------------------
// semb = leaky(LN(num/den + b)); head MLP; out[m]
// one 64-lane wave per node, 4 nodes per block
// ---------------------------------------------------------------------------
__global__ __launch_bounds__(256)
void finalize_kernel(const float* __restrict__ num, const float* __restrict__ den,
                     const float* __restrict__ gatb,
                     const float* __restrict__ ln2g, const float* __restrict__ ln2b,
                     const float* __restrict__ W1, const float* __restrict__ b1,
                     const float* __restrict__ W2, const float* __restrict__ b2,
                     float* __restrict__ out)
{
  __shared__ float sW1[SH_ * 32];
  __shared__ float sb1[32], sW2[32];
  __shared__ float ssemb[4][SH_ + 1];

  const int tid = threadIdx.x;
  for (int i = tid; i < SH_ * 32; i += 256) sW1[i] = W1[i];
  if (tid < 32) { sb1[tid] = b1[tid]; sW2[tid] = W2[tid]; }

  const int lane = tid & 63, grp = tid >> 6;
  const int m = blockIdx.x * 4 + grp;

  const float v = num[(size_t)m * 64 + lane] / den[m * 4 + (lane >> 4)] + gatb[lane];

  float s = v;
#pragma unroll
  for (int o = 32; o >= 1; o >>= 1) s += __shfl_xor(s, o, 64);
  const float mu = s * (1.0f / 64.0f);
  const float d0 = v - mu;
  float s2 = d0 * d0;
#pragma unroll
  for (int o = 32; o >= 1; o >>= 1) s2 += __shfl_xor(s2, o, 64);
  const float var = s2 * (1.0f / 64.0f);
  float sem = d0 * rsqrtf(var + 1e-5f) * ln2g[lane] + ln2b[lane];
  sem = leaky_(sem);

  ssemb[grp][lane] = sem;
  __syncthreads();

  float contrib = 0.0f;
  if (lane < 32) {
    float acc = sb1[lane];
    for (int c = 0; c < SH_; ++c) acc += ssemb[grp][c] * sW1[c * 32 + lane];
    acc = leaky_(acc);
    contrib = acc * sW2[lane];
  }
#pragma unroll
  for (int o = 32; o >= 1; o >>= 1) contrib += __shfl_xor(contrib, o, 64);
  if (lane == 0) out[m] = contrib + b2[0];
}

// ---------------------------------------------------------------------------
extern "C" void kernel_launch(void* const* d_in, const int* in_sizes, int n_in,
                              void* d_out, int out_size, void* d_ws, size_t ws_size,
                              hipStream_t stream)
{
  const float* x    = (const float*)d_in[0];
  const int*   ei   = (const int*)d_in[1];
  const float* Wih0 = (const float*)d_in[2];
  const float* Whh0 = (const float*)d_in[3];
  const float* bih0 = (const float*)d_in[4];
  const float* bhh0 = (const float*)d_in[5];
  const float* Wih1 = (const float*)d_in[6];
  const float* Whh1 = (const float*)d_in[7];
  const float* bih1 = (const float*)d_in[8];
  const float* bhh1 = (const float*)d_in[9];
  const float* ln1g = (const float*)d_in[10];
  const float* ln1b = (const float*)d_in[11];
  const float* gatW = (const float*)d_in[12];
  const float* attS = (const float*)d_in[13];
  const float* attD = (const float*)d_in[14];
  const float* gatb = (const float*)d_in[15];
  const float* ln2g = (const float*)d_in[16];
  const float* ln2b = (const float*)d_in[17];
  const float* W1   = (const float*)d_in[18];
  const float* b1   = (const float*)d_in[19];
  const float* W2   = (const float*)d_in[20];
  const float* b2   = (const float*)d_in[21];
  float* out = (float*)d_out;

  const int EB = in_sizes[1] / 2;

  float* ws = (float*)d_ws;
  float*    temb = ws;                                   // M*128
  float*    xp   = temb + (size_t)M_ * TH_;              // M*64
  float*    asrc = xp + (size_t)M_ * 64;                 // M*4
  float*    adst = asrc + (size_t)M_ * 4;                // M*4
  unsigned* amax = (unsigned*)(adst + (size_t)M_ * 4);   // M*4
  float*    den  = (float*)(amax + (size_t)M_ * 4);      // M*4
  float*    num  = den + (size_t)M_ * 4;                 // M*64

  gru_kernel<<<M_ / NPB, 256, 0, stream>>>(x, Wih0, Whh0, bih0, bhh0,
                                           Wih1, Whh1, bih1, bhh1, ln1g, ln1b, temb);
  init_kernel<<<(M_ * 64 + 255) / 256, 256, 0, stream>>>(amax, den, num);
  gat_xp_kernel<<<M_ / 64, 256, 0, stream>>>(temb, gatW, attS, attD, xp, asrc, adst);

  const int ET = B_ * EB + M_;
  edge_amax_kernel<<<(ET + 255) / 256, 256, 0, stream>>>(ei, EB, asrc, adst, amax);
  edge_sum_kernel<<<(ET + 255) / 256, 256, 0, stream>>>(ei, EB, asrc, adst, amax, xp, den, num);
  finalize_kernel<<<M_ / 4, 256, 0, stream>>>(num, den, gatb, ln2g, ln2b, W1, b1, W2, b2, out);
}

// Round 2
// 5118.004 us; speedup vs baseline: 1.6866x; 1.6866x over previous
//
#include <hip/hip_runtime.h>
#include <math.h>

#define B_   16
#define N_   2000
#define W_   32
#define F_   5
#define TH_  128
#define M_   (B_*N_)   // 32000
#define SH_  64
#define NPB  64        // nodes per block in GRU kernel

typedef unsigned short u16;
typedef short short8 __attribute__((ext_vector_type(8)));
typedef float f32x4  __attribute__((ext_vector_type(4)));

__device__ __forceinline__ float sigmoidf_(float x) { return 1.0f / (1.0f + expf(-x)); }
__device__ __forceinline__ float leaky_(float x)    { return x > 0.0f ? x : 0.2f * x; }

// round-to-nearest-even fp32 -> bf16 bits
__device__ __forceinline__ u16 f2bf(float f) {
  unsigned u = __float_as_uint(f);
  unsigned r = (u + 0x7FFFu + ((u >> 16) & 1u)) >> 16;
  return (u16)r;
}
__device__ __forceinline__ float bf2f(u16 h) { return __uint_as_float(((unsigned)h) << 16); }

__device__ __forceinline__ f32x4 mfma3(short8 ah, short8 al, short8 bh, short8 bl, f32x4 c) {
  c = __builtin_amdgcn_mfma_f32_16x16x32_bf16(ah, bh, c, 0, 0, 0);
  c = __builtin_amdgcn_mfma_f32_16x16x32_bf16(al, bh, c, 0, 0, 0);
  c = __builtin_amdgcn_mfma_f32_16x16x32_bf16(ah, bl, c, 0, 0, 0);
  return c;
}

// LDS h layout: dword = node*128 + ((u&~3) ^ ((node&7)<<2)) + (u&3)
__device__ __forceinline__ int haddr(int node, int u) {
  return node * 128 + (((u & ~3) ^ ((node & 7) << 2))) + (u & 3);
}

__device__ __forceinline__ void load_afrag(const float* hb, int node, int u0,
                                           short8& ah, short8& al) {
  const int sw = (node & 7) << 2;
  const float4 a = *(const float4*)(hb + node * 128 + (u0 ^ sw));
  const float4 b = *(const float4*)(hb + node * 128 + ((u0 + 4) ^ sw));
  float v[8] = {a.x, a.y, a.z, a.w, b.x, b.y, b.z, b.w};
#pragma unroll
  for (int j = 0; j < 8; ++j) {
    const u16 h = f2bf(v[j]);
    ah[j] = (short)h;
    al[j] = (short)f2bf(v[j] - bf2f(h));
  }
}

// ---------------------------------------------------------------------------
// Prologue: split fp32 weights into bf16 hi/lo (Wih0 K-padded 5->32)
// ---------------------------------------------------------------------------
#define S0_ (384*32)
#define S1_ (384*128)
__global__ void splitw_kernel(const float* __restrict__ Wih0, const float* __restrict__ Whh0,
                              const float* __restrict__ Wih1, const float* __restrict__ Whh1,
                              u16* __restrict__ wsp)
{
  const int i = blockIdx.x * 256 + threadIdx.x;
  float v; u16 *ph, *pl; int idx;
  if (i < S0_) {
    const int row = i >> 5, k = i & 31;
    v = (k < F_) ? Wih0[row * F_ + k] : 0.0f;
    ph = wsp; pl = wsp + S0_; idx = i;
  } else {
    const int j = i - S0_;
    if (j < S1_)            { v = Whh0[j];          ph = wsp + 2*S0_;          idx = j; }
    else if (j < 2*S1_)     { v = Wih1[j - S1_];    ph = wsp + 2*S0_ + 2*S1_;  idx = j - S1_; }
    else if (j < 3*S1_)     { v = Whh1[j - 2*S1_];  ph = wsp + 2*S0_ + 4*S1_;  idx = j - 2*S1_; }
    else return;
    pl = ph + S1_;
  }
  const u16 h = f2bf(v);
  ph[idx] = h;
  pl[idx] = f2bf(v - bf2f(h));
}

// ---------------------------------------------------------------------------
// Fused 2-layer GRU via split-bf16 MFMA + LayerNorm -> temb [M][128]
// ---------------------------------------------------------------------------
__global__ __launch_bounds__(256, 2)
void gru_mfma_kernel(const float* __restrict__ x,
                     const u16* __restrict__ wih0h, const u16* __restrict__ wih0l,
                     const u16* __restrict__ whh0h, const u16* __restrict__ whh0l,
                     const u16* __restrict__ wih1h, const u16* __restrict__ wih1l,
                     const u16* __restrict__ whh1h, const u16* __restrict__ whh1l,
                     const float* __restrict__ bih0, const float* __restrict__ bhh0,
                     const float* __restrict__ bih1, const float* __restrict__ bhh1,
                     const float* __restrict__ ln1g, const float* __restrict__ ln1b,
                     float* __restrict__ temb)
{
  __shared__ float h0s[NPB * 128];
  __shared__ float h1s[NPB * 128];

  const int tid = threadIdx.x;
  const int lane = tid & 63, wv = tid >> 6, q = lane >> 4, li = lane & 15;
  const int mbase = blockIdx.x * NPB;

  for (int i = tid; i < NPB * 128; i += 256) { h0s[i] = 0.0f; h1s[i] = 0.0f; }

  // per-wave column ownership: unit tiles (wv*2+ut)
  int roff[3][2], roffI[3][2];
  float BR0v[2], BZ0v[2], BNI0v[2], BNH0v[2];
  float BR1v[2], BZ1v[2], BNI1v[2], BNH1v[2];
#pragma unroll
  for (int ut = 0; ut < 2; ++ut) {
    const int colU = (wv * 2 + ut) * 16;
    const int unit = colU + li;
#pragma unroll
    for (int g = 0; g < 3; ++g) {
      roff[g][ut]  = (g * TH_ + colU + li) * TH_;
      roffI[g][ut] = (g * TH_ + colU + li) * 32;
    }
    BR0v[ut]  = bih0[unit] + bhh0[unit];
    BZ0v[ut]  = bih0[TH_ + unit] + bhh0[TH_ + unit];
    BNI0v[ut] = bih0[2 * TH_ + unit];
    BNH0v[ut] = bhh0[2 * TH_ + unit];
    BR1v[ut]  = bih1[unit] + bhh1[unit];
    BZ1v[ut]  = bih1[TH_ + unit] + bhh1[TH_ + unit];
    BNI1v[ut] = bih1[2 * TH_ + unit];
    BNH1v[ut] = bhh1[2 * TH_ + unit];
  }
  const f32x4 z4 = {0.0f, 0.0f, 0.0f, 0.0f};
  __syncthreads();

  f32x4 aR[4][2], aZ[4][2], aNI[4][2], aNH[4][2];

  for (int t = 0; t < W_; ++t) {
    // ---------- layer0: ih (K=32, padded) ----------
    short8 xh[4], xl[4];
#pragma unroll
    for (int nt = 0; nt < 4; ++nt) {
      float v[8] = {0, 0, 0, 0, 0, 0, 0, 0};
      if (q == 0) {
        const float* px = x + (size_t)(mbase + nt * 16 + li) * (W_ * F_) + t * F_;
        v[0] = px[0]; v[1] = px[1]; v[2] = px[2]; v[3] = px[3]; v[4] = px[4];
      }
#pragma unroll
      for (int j = 0; j < 8; ++j) {
        const u16 h = f2bf(v[j]);
        xh[nt][j] = (short)h;
        xl[nt][j] = (short)f2bf(v[j] - bf2f(h));
      }
    }
#pragma unroll
    for (int ut = 0; ut < 2; ++ut)
#pragma unroll
      for (int g = 0; g < 3; ++g) {
        const int ro = roffI[g][ut] + q * 8;
        const short8 bh = *(const short8*)(wih0h + ro);
        const short8 bl = *(const short8*)(wih0l + ro);
#pragma unroll
        for (int nt = 0; nt < 4; ++nt) {
          const f32x4 c = mfma3(xh[nt], xl[nt], bh, bl, z4);
          if (g == 0) aR[nt][ut] = c; else if (g == 1) aZ[nt][ut] = c; else aNI[nt][ut] = c;
        }
      }

    // ---------- layer0: hh (K=128) ----------
#pragma unroll
    for (int kt = 0; kt < 4; ++kt) {
      short8 Ah[4], Al[4];
#pragma unroll
      for (int nt = 0; nt < 4; ++nt)
        load_afrag(h0s, nt * 16 + li, kt * 32 + q * 8, Ah[nt], Al[nt]);
#pragma unroll
      for (int ut = 0; ut < 2; ++ut)
#pragma unroll
        for (int g = 0; g < 3; ++g) {
          const int ro = roff[g][ut] + kt * 32 + q * 8;
          const short8 bh = *(const short8*)(whh0h + ro);
          const short8 bl = *(const short8*)(whh0l + ro);
#pragma unroll
          for (int nt = 0; nt < 4; ++nt) {
            f32x4 c;
            if (g == 0)      c = aR[nt][ut];
            else if (g == 1) c = aZ[nt][ut];
            else             c = (kt == 0) ? z4 : aNH[nt][ut];
            c = mfma3(Ah[nt], Al[nt], bh, bl, c);
            if (g == 0) aR[nt][ut] = c; else if (g == 1) aZ[nt][ut] = c; else aNH[nt][ut] = c;
          }
        }
    }
    __syncthreads();  // all h0 reads done

    // ---------- gates layer0 -> h0 (own columns only) ----------
#pragma unroll
    for (int ut = 0; ut < 2; ++ut) {
      const int unit = (wv * 2 + ut) * 16 + li;
#pragma unroll
      for (int nt = 0; nt < 4; ++nt)
#pragma unroll
        for (int r = 0; r < 3 + 1; ++r) {
          const int node = nt * 16 + q * 4 + r;
          const float rr = sigmoidf_(aR[nt][ut][r] + BR0v[ut]);
          const float zz = sigmoidf_(aZ[nt][ut][r] + BZ0v[ut]);
          const float nn = tanhf(aNI[nt][ut][r] + BNI0v[ut] + rr * (aNH[nt][ut][r] + BNH0v[ut]));
          const int ad = haddr(node, unit);
          h0s[ad] = (1.0f - zz) * nn + zz * h0s[ad];
        }
    }
    __syncthreads();  // h0 new visible

    // ---------- layer1: ih (A=h0 new) + hh (A=h1), K=128 each ----------
#pragma unroll
    for (int kt = 0; kt < 4; ++kt) {
      short8 Ah[4], Al[4];
#pragma unroll
      for (int nt = 0; nt < 4; ++nt)
        load_afrag(h0s, nt * 16 + li, kt * 32 + q * 8, Ah[nt], Al[nt]);
#pragma unroll
      for (int ut = 0; ut < 2; ++ut)
#pragma unroll
        for (int g = 0; g < 3; ++g) {
          const int ro = roff[g][ut] + kt * 32 + q * 8;
          const short8 bh = *(const short8*)(wih1h + ro);
          const short8 bl = *(const short8*)(wih1l + ro);
#pragma unroll
          for (int nt = 0; nt < 4; ++nt) {
            f32x4 c;
            if (g == 0)      c = (kt == 0) ? z4 : aR[nt][ut];
            else if (g == 1) c = (kt == 0) ? z4 : aZ[nt][ut];
            else             c = (kt == 0) ? z4 : aNI[nt][ut];
            c = mfma3(Ah[nt], Al[nt], bh, bl, c);
            if (g == 0) aR[nt][ut] = c; else if (g == 1) aZ[nt][ut] = c; else aNI[nt][ut] = c;
          }
        }
    }
#pragma unroll
    for (int kt = 0; kt < 4; ++kt) {
      short8 Ah[4], Al[4];
#pragma unroll
      for (int nt = 0; nt < 4; ++nt)
        load_afrag(h1s, nt * 16 + li, kt * 32 + q * 8, Ah[nt], Al[nt]);
#pragma unroll
      for (int ut = 0; ut < 2; ++ut)
#pragma unroll
        for (int g = 0; g < 3; ++g) {
          const int ro = roff[g][ut] + kt * 32 + q * 8;
          const short8 bh = *(const short8*)(whh1h + ro);
          const short8 bl = *(const short8*)(whh1l + ro);
#pragma unroll
          for (int nt = 0; nt < 4; ++nt) {
            f32x4 c;
            if (g == 0)      c = aR[nt][ut];
            else if (g == 1) c = aZ[nt][ut];
            else             c = (kt == 0) ? z4 : aNH[nt][ut];
            c = mfma3(Ah[nt], Al[nt], bh, bl, c);
            if (g == 0) aR[nt][ut] = c; else if (g == 1) aZ[nt][ut] = c; else aNH[nt][ut] = c;
          }
        }
    }
    __syncthreads();  // all h1/h0 reads done

    // ---------- gates layer1 -> h1 ----------
#pragma unroll
    for (int ut = 0; ut < 2; ++ut) {
      const int unit = (wv * 2 + ut) * 16 + li;
#pragma unroll
      for (int nt = 0; nt < 4; ++nt)
#pragma unroll
        for (int r = 0; r < 4; ++r) {
          const int node = nt * 16 + q * 4 + r;
          const float rr = sigmoidf_(aR[nt][ut][r] + BR1v[ut]);
          const float zz = sigmoidf_(aZ[nt][ut][r] + BZ1v[ut]);
          const float nn = tanhf(aNI[nt][ut][r] + BNI1v[ut] + rr * (aNH[nt][ut][r] + BNH1v[ut]));
          const int ad = haddr(node, unit);
          h1s[ad] = (1.0f - zz) * nn + zz * h1s[ad];
        }
    }
    __syncthreads();
  }

  // ---------- LayerNorm(h1) -> temb ----------
  const int n = tid >> 2, qq = tid & 3;
  float vr[32];
  float s = 0.0f;
#pragma unroll
  for (int k = 0; k < 8; ++k) {
    const int u = qq * 32 + k * 4;
    const float4 v = *(const float4*)(h1s + n * 128 + ((u) ^ ((n & 7) << 2)));
    vr[k * 4 + 0] = v.x; vr[k * 4 + 1] = v.y; vr[k * 4 + 2] = v.z; vr[k * 4 + 3] = v.w;
    s += v.x + v.y + v.z + v.w;
  }
  s += __shfl_xor(s, 1, 64); s += __shfl_xor(s, 2, 64);
  const float mu = s * (1.0f / TH_);
  float s2 = 0.0f;
#pragma unroll
  for (int k = 0; k < 32; ++k) { const float d = vr[k] - mu; s2 += d * d; }
  s2 += __shfl_xor(s2, 1, 64); s2 += __shfl_xor(s2, 2, 64);
  const float inv = rsqrtf(s2 * (1.0f / TH_) + 1e-5f);
  float* to = temb + (size_t)(mbase + n) * TH_ + qq * 32;
#pragma unroll
  for (int k = 0; k < 32; ++k)
    to[k] = (vr[k] - mu) * inv * ln1g[qq * 32 + k] + ln1b[qq * 32 + k];
}

// ---------------------------------------------------------------------------
// xp = temb @ gat_W -> [M][64]; a_src/a_dst -> [M][4]
// ---------------------------------------------------------------------------
__global__ __launch_bounds__(256)
void gat_xp_kernel(const float* __restrict__ temb, const float* __restrict__ gatW,
                   const float* __restrict__ attS, const float* __restrict__ attD,
                   float* __restrict__ xp, float* __restrict__ asrc, float* __restrict__ adst)
{
  __shared__ float ts[64][TH_ + 4];
  __shared__ float4 ws4[TH_][16];
  __shared__ float sa[64], sd[64];

  const int tid = threadIdx.x;
  const int mbase = blockIdx.x * 64;

  for (int i = tid; i < 64 * TH_; i += 256) {
    const int n = i >> 7, k = i & 127;
    ts[n][k] = temb[(size_t)mbase * TH_ + i];
  }
  for (int i = tid; i < TH_ * 16; i += 256)
    ((float4*)ws4)[i] = ((const float4*)gatW)[i];
  if (tid < 64) { sa[tid] = attS[tid]; sd[tid] = attD[tid]; }
  __syncthreads();

  const int nl = tid >> 2;
  const int q  = tid & 3;
  float4 acc[4];
#pragma unroll
  for (int i = 0; i < 4; ++i) acc[i] = make_float4(0.f, 0.f, 0.f, 0.f);

  for (int k = 0; k < TH_; ++k) {
    const float tv = ts[nl][k];
#pragma unroll
    for (int c0 = 0; c0 < 4; ++c0) {
      const float4 wv = ws4[k][q * 4 + c0];
      acc[c0].x += tv * wv.x; acc[c0].y += tv * wv.y;
      acc[c0].z += tv * wv.z; acc[c0].w += tv * wv.w;
    }
  }

  float as = 0.0f, ad = 0.0f;
#pragma unroll
  for (int c0 = 0; c0 < 4; ++c0) {
    const int base = q * 16 + c0 * 4;
    as += acc[c0].x * sa[base + 0] + acc[c0].y * sa[base + 1] +
          acc[c0].z * sa[base + 2] + acc[c0].w * sa[base + 3];
    ad += acc[c0].x * sd[base + 0] + acc[c0].y * sd[base + 1] +
          acc[c0].z * sd[base + 2] + acc[c0].w * sd[base + 3];
  }

  const int m = mbase + nl;
  asrc[m * 4 + q] = as;
  adst[m * 4 + q] = ad;
  float4* xpo = (float4*)&xp[(size_t)m * 64 + q * 16];
#pragma unroll
  for (int c0 = 0; c0 < 4; ++c0) xpo[c0] = acc[c0];
}

// ---------------------------------------------------------------------------
__global__ void init_kernel(float* __restrict__ den, float* __restrict__ num)
{
  const int i = blockIdx.x * 256 + threadIdx.x;
  if (i < M_ * 4) den[i] = 0.0f;
  if (i < M_ * 64) num[i] = 0.0f;
}

// exp(alpha) without segment-max: algebraically identical softmax, alpha is O(1)
__global__ void edge_sum_kernel(const int* __restrict__ ei, const int EB,
                                const float* __restrict__ asrc, const float* __restrict__ adst,
                                const float* __restrict__ xp,
                                float* __restrict__ den, float* __restrict__ num)
{
  const int e = blockIdx.x * 256 + threadIdx.x;
  const int ET = B_ * EB + M_;
  if (e >= ET) return;
  int s, d;
  if (e < B_ * EB) {
    const int b = e / EB, r = e - b * EB, off = b * N_;
    s = ei[r] + off;
    d = ei[EB + r] + off;
  } else {
    s = d = e - B_ * EB;
  }
  const float4 as = *(const float4*)&asrc[s * 4];
  const float4 ad = *(const float4*)&adst[d * 4];
  float ex[4];
  ex[0] = expf(leaky_(as.x + ad.x));
  ex[1] = expf(leaky_(as.y + ad.y));
  ex[2] = expf(leaky_(as.z + ad.z));
  ex[3] = expf(leaky_(as.w + ad.w));
  unsafeAtomicAdd(&den[d * 4 + 0], ex[0]);
  unsafeAtomicAdd(&den[d * 4 + 1], ex[1]);
  unsafeAtomicAdd(&den[d * 4 + 2], ex[2]);
  unsafeAtomicAdd(&den[d * 4 + 3], ex[3]);

  const float4* xps = (const float4*)&xp[(size_t)s * 64];
  float* nd = &num[(size_t)d * 64];
#pragma unroll
  for (int cq = 0; cq < 16; ++cq) {
    const float4 v = xps[cq];
    const float w = ex[cq >> 2];
    unsafeAtomicAdd(&nd[cq * 4 + 0], w * v.x);
    unsafeAtomicAdd(&nd[cq * 4 + 1], w * v.y);
    unsafeAtomicAdd(&nd[cq * 4 + 2], w * v.z);
    unsafeAtomicAdd(&nd[cq * 4 + 3], w * v.w);
  }
}

// ---------------------------------------------------------------------------
__global__ __launch_bounds__(256)
void finalize_kernel(const float* __restrict__ num, const float* __restrict__ den,
                     const float* __restrict__ gatb,
                     const float* __restrict__ ln2g, const float* __restrict__ ln2b,
                     const float* __restrict__ W1, const float* __restrict__ b1,
                     const float* __restrict__ W2, const float* __restrict__ b2,
                     float* __restrict__ out)
{
  __shared__ float sW1[SH_ * 32];
  __shared__ float sb1[32], sW2[32];
  __shared__ float ssemb[4][SH_ + 1];

  const int tid = threadIdx.x;
  for (int i = tid; i < SH_ * 32; i += 256) sW1[i] = W1[i];
  if (tid < 32) { sb1[tid] = b1[tid]; sW2[tid] = W2[tid]; }

  const int lane = tid & 63, grp = tid >> 6;
  const int m = blockIdx.x * 4 + grp;

  const float v = num[(size_t)m * 64 + lane] / den[m * 4 + (lane >> 4)] + gatb[lane];

  float s = v;
#pragma unroll
  for (int o = 32; o >= 1; o >>= 1) s += __shfl_xor(s, o, 64);
  const float mu = s * (1.0f / 64.0f);
  const float d0 = v - mu;
  float s2 = d0 * d0;
#pragma unroll
  for (int o = 32; o >= 1; o >>= 1) s2 += __shfl_xor(s2, o, 64);
  const float var = s2 * (1.0f / 64.0f);
  float sem = d0 * rsqrtf(var + 1e-5f) * ln2g[lane] + ln2b[lane];
  sem = leaky_(sem);

  ssemb[grp][lane] = sem;
  __syncthreads();

  float contrib = 0.0f;
  if (lane < 32) {
    float acc = sb1[lane];
    for (int c = 0; c < SH_; ++c) acc += ssemb[grp][c] * sW1[c * 32 + lane];
    acc = leaky_(acc);
    contrib = acc * sW2[lane];
  }
#pragma unroll
  for (int o = 32; o >= 1; o >>= 1) contrib += __shfl_xor(contrib, o, 64);
  if (lane == 0) out[m] = contrib + b2[0];
}

// ---------------------------------------------------------------------------
extern "C" void kernel_launch(void* const* d_in, const int* in_sizes, int n_in,
                              void* d_out, int out_size, void* d_ws, size_t ws_size,
                              hipStream_t stream)
{
  const float* x    = (const float*)d_in[0];
  const int*   ei   = (const int*)d_in[1];
  const float* Wih0 = (const float*)d_in[2];
  const float* Whh0 = (const float*)d_in[3];
  const float* bih0 = (const float*)d_in[4];
  const float* bhh0 = (const float*)d_in[5];
  const float* Wih1 = (const float*)d_in[6];
  const float* Whh1 = (const float*)d_in[7];
  const float* bih1 = (const float*)d_in[8];
  const float* bhh1 = (const float*)d_in[9];
  const float* ln1g = (const float*)d_in[10];
  const float* ln1b = (const float*)d_in[11];
  const float* gatW = (const float*)d_in[12];
  const float* attS = (const float*)d_in[13];
  const float* attD = (const float*)d_in[14];
  const float* gatb = (const float*)d_in[15];
  const float* ln2g = (const float*)d_in[16];
  const float* ln2b = (const float*)d_in[17];
  const float* W1   = (const float*)d_in[18];
  const float* b1   = (const float*)d_in[19];
  const float* W2   = (const float*)d_in[20];
  const float* b2   = (const float*)d_in[21];
  float* out = (float*)d_out;

  const int EB = in_sizes[1] / 2;

  float* ws = (float*)d_ws;
  float* temb = ws;                                  // M*128
  float* xp   = temb + (size_t)M_ * TH_;             // M*64
  float* asrc = xp + (size_t)M_ * 64;                // M*4
  float* adst = asrc + (size_t)M_ * 4;               // M*4
  float* den  = adst + (size_t)M_ * 4;               // M*4
  float* num  = den + (size_t)M_ * 4;                // M*64
  u16*   wsp  = (u16*)(num + (size_t)M_ * 64);       // split weights (bf16 hi/lo)

  const u16* wih0h = wsp;
  const u16* wih0l = wsp + S0_;
  const u16* whh0h = wsp + 2 * S0_;
  const u16* whh0l = whh0h + S1_;
  const u16* wih1h = whh0l + S1_;
  const u16* wih1l = wih1h + S1_;
  const u16* whh1h = wih1l + S1_;
  const u16* whh1l = whh1h + S1_;

  const int NSPLIT = S0_ + 3 * S1_;
  splitw_kernel<<<(NSPLIT + 255) / 256, 256, 0, stream>>>(Wih0, Whh0, Wih1, Whh1, wsp);

  gru_mfma_kernel<<<M_ / NPB, 256, 0, stream>>>(
      x, wih0h, wih0l, whh0h, whh0l, wih1h, wih1l, whh1h, whh1l,
      bih0, bhh0, bih1, bhh1, ln1g, ln1b, temb);

  init_kernel<<<(M_ * 64 + 255) / 256, 256, 0, stream>>>(den, num);
  gat_xp_kernel<<<M_ / 64, 256, 0, stream>>>(temb, gatW, attS, attD, xp, asrc, adst);

  const int ET = B_ * EB + M_;
  edge_sum_kernel<<<(ET + 255) / 256, 256, 0, stream>>>(ei, EB, asrc, adst, xp, den, num);
  finalize_kernel<<<M_ / 4, 256, 0, stream>>>(num, den, gatb, ln2g, ln2b, W1, b1, W2, b2, out);
}

// Round 3
// 2269.003 us; speedup vs baseline: 3.8042x; 2.2556x over previous
//
#include <hip/hip_runtime.h>
#include <math.h>

#define B_   16
#define N_   2000
#define W_   32
#define F_   5
#define TH_  128
#define M_   (B_*N_)   // 32000
#define SH_  64
#define NPB  128       // nodes per block in GRU kernel (512 threads, 8 waves)

typedef unsigned short u16;
typedef short short8 __attribute__((ext_vector_type(8)));
typedef float f32x4  __attribute__((ext_vector_type(4)));

__device__ __forceinline__ float leaky_(float x) { return x > 0.0f ? x : 0.2f * x; }
__device__ __forceinline__ float sigm_(float x) {
  return __fdividef(1.0f, 1.0f + __expf(-x));
}
__device__ __forceinline__ float tanh_(float x) {
  const float e2 = __expf(2.0f * x);
  return 1.0f - __fdividef(2.0f, e2 + 1.0f);
}

// round-to-nearest-even fp32 -> bf16 bits
__device__ __forceinline__ u16 f2bf(float f) {
  unsigned u = __float_as_uint(f);
  unsigned r = (u + 0x7FFFu + ((u >> 16) & 1u)) >> 16;
  return (u16)r;
}
__device__ __forceinline__ float bf2f(u16 h) { return __uint_as_float(((unsigned)h) << 16); }

__device__ __forceinline__ f32x4 mfma3(short8 ah, short8 al, short8 bh, short8 bl, f32x4 c) {
  c = __builtin_amdgcn_mfma_f32_16x16x32_bf16(ah, bh, c, 0, 0, 0);
  c = __builtin_amdgcn_mfma_f32_16x16x32_bf16(al, bh, c, 0, 0, 0);
  c = __builtin_amdgcn_mfma_f32_16x16x32_bf16(ah, bl, c, 0, 0, 0);
  return c;
}

// ---------------------------------------------------------------------------
// Prologue: split fp32 weights into bf16 hi/lo (Wih0 K-padded 5->32)
// ---------------------------------------------------------------------------
#define S0_ (384*32)
#define S1_ (384*128)
__global__ void splitw_kernel(const float* __restrict__ Wih0, const float* __restrict__ Whh0,
                              const float* __restrict__ Wih1, const float* __restrict__ Whh1,
                              u16* __restrict__ wsp)
{
  const int i = blockIdx.x * 256 + threadIdx.x;
  float v; u16 *ph, *pl; int idx;
  if (i < S0_) {
    const int row = i >> 5, k = i & 31;
    v = (k < F_) ? Wih0[row * F_ + k] : 0.0f;
    ph = wsp; pl = wsp + S0_; idx = i;
  } else {
    const int j = i - S0_;
    if (j < S1_)            { v = Whh0[j];          ph = wsp + 2*S0_;          idx = j; }
    else if (j < 2*S1_)     { v = Wih1[j - S1_];    ph = wsp + 2*S0_ + 2*S1_;  idx = j - S1_; }
    else if (j < 3*S1_)     { v = Whh1[j - 2*S1_];  ph = wsp + 2*S0_ + 4*S1_;  idx = j - 2*S1_; }
    else return;
    pl = ph + S1_;
  }
  const u16 h = f2bf(v);
  ph[idx] = h;
  pl[idx] = f2bf(v - bf2f(h));
}

// ---------------------------------------------------------------------------
// Fused 2-layer GRU via split-bf16 MFMA + LayerNorm -> temb [M][128]
// h stored in LDS as bf16 hi/lo planes, k-contiguous per node, 16B-XOR-swizzled
// ---------------------------------------------------------------------------
__global__ __launch_bounds__(512, 2)
void gru_mfma_kernel(const float* __restrict__ x,
                     const u16* __restrict__ wih0h, const u16* __restrict__ wih0l,
                     const u16* __restrict__ whh0h, const u16* __restrict__ whh0l,
                     const u16* __restrict__ wih1h, const u16* __restrict__ wih1l,
                     const u16* __restrict__ whh1h, const u16* __restrict__ whh1l,
                     const float* __restrict__ bih0, const float* __restrict__ bhh0,
                     const float* __restrict__ bih1, const float* __restrict__ bhh1,
                     const float* __restrict__ ln1g, const float* __restrict__ ln1b,
                     float* __restrict__ temb)
{
  __shared__ u16 h0hi[NPB * TH_], h0lo[NPB * TH_];
  __shared__ u16 h1hi[NPB * TH_], h1lo[NPB * TH_];

  const int tid = threadIdx.x;
  const int lane = tid & 63, wv = tid >> 6, q = lane >> 4, li = lane & 15;
  const int mbase = blockIdx.x * NPB;
  const int unit = wv * 16 + li;   // each wave owns one 16-unit column tile

  for (int i = tid; i < NPB * TH_ / 2; i += 512) {
    ((unsigned*)h0hi)[i] = 0u; ((unsigned*)h0lo)[i] = 0u;
    ((unsigned*)h1hi)[i] = 0u; ((unsigned*)h1lo)[i] = 0u;
  }

  int roff[3], roffI[3];
#pragma unroll
  for (int g = 0; g < 3; ++g) {
    roff[g]  = (g * TH_ + unit) * TH_;
    roffI[g] = (g * TH_ + unit) * 32;
  }
  const float BR0  = bih0[unit] + bhh0[unit];
  const float BZ0  = bih0[TH_ + unit] + bhh0[TH_ + unit];
  const float BNI0 = bih0[2 * TH_ + unit];
  const float BNH0 = bhh0[2 * TH_ + unit];
  const float BR1  = bih1[unit] + bhh1[unit];
  const float BZ1  = bih1[TH_ + unit] + bhh1[TH_ + unit];
  const float BNI1 = bih1[2 * TH_ + unit];
  const float BNH1 = bhh1[2 * TH_ + unit];
  const f32x4 z4 = {0.0f, 0.0f, 0.0f, 0.0f};
  __syncthreads();

  f32x4 aR[8], aZ[8], aNI[8], aNH[8];

  for (int t = 0; t < W_; ++t) {
    // ---------- layer0: ih (K=32, padded) ----------
    {
      short8 xh[8], xl[8];
#pragma unroll
      for (int nt = 0; nt < 8; ++nt) {
        float v[8] = {0, 0, 0, 0, 0, 0, 0, 0};
        if (q == 0) {
          const float* px = x + (size_t)(mbase + nt * 16 + li) * (W_ * F_) + t * F_;
          v[0] = px[0]; v[1] = px[1]; v[2] = px[2]; v[3] = px[3]; v[4] = px[4];
        }
#pragma unroll
        for (int j = 0; j < 8; ++j) {
          const u16 h = f2bf(v[j]);
          xh[nt][j] = (short)h;
          xl[nt][j] = (short)f2bf(v[j] - bf2f(h));
        }
      }
#pragma unroll
      for (int g = 0; g < 3; ++g) {
        const int ro = roffI[g] + q * 8;
        const short8 bh = *(const short8*)(wih0h + ro);
        const short8 bl = *(const short8*)(wih0l + ro);
#pragma unroll
        for (int nt = 0; nt < 8; ++nt) {
          const f32x4 c = mfma3(xh[nt], xl[nt], bh, bl, z4);
          if (g == 0) aR[nt] = c; else if (g == 1) aZ[nt] = c; else aNI[nt] = c;
        }
      }
    }

    // ---------- layer0: hh (K=128) ----------
#pragma unroll
    for (int kt = 0; kt < 4; ++kt) {
      short8 Ah[8], Al[8];
#pragma unroll
      for (int nt = 0; nt < 8; ++nt) {
        const int node = nt * 16 + li;
        const int g16 = ((kt * 4 + q) ^ (node & 15)) * 8;
        Ah[nt] = *(const short8*)(h0hi + node * TH_ + g16);
        Al[nt] = *(const short8*)(h0lo + node * TH_ + g16);
      }
#pragma unroll
      for (int g = 0; g < 3; ++g) {
        const int ro = roff[g] + kt * 32 + q * 8;
        const short8 bh = *(const short8*)(whh0h + ro);
        const short8 bl = *(const short8*)(whh0l + ro);
#pragma unroll
        for (int nt = 0; nt < 8; ++nt) {
          f32x4 c;
          if (g == 0)      c = aR[nt];
          else if (g == 1) c = aZ[nt];
          else             c = (kt == 0) ? z4 : aNH[nt];
          c = mfma3(Ah[nt], Al[nt], bh, bl, c);
          if (g == 0) aR[nt] = c; else if (g == 1) aZ[nt] = c; else aNH[nt] = c;
        }
      }
    }
    __syncthreads();  // all h0 reads done

    // ---------- gates layer0 -> h0 planes ----------
#pragma unroll
    for (int nt = 0; nt < 8; ++nt)
#pragma unroll
      for (int r = 0; r < 4; ++r) {
        const int node = nt * 16 + q * 4 + r;
        const int idx = node * TH_ + (((unit >> 3) ^ (node & 15)) << 3) + (unit & 7);
        const float hold = bf2f(h0hi[idx]) + bf2f(h0lo[idx]);
        const float rr = sigm_(aR[nt][r] + BR0);
        const float zz = sigm_(aZ[nt][r] + BZ0);
        const float nn = tanh_(aNI[nt][r] + BNI0 + rr * (aNH[nt][r] + BNH0));
        const float hv = (1.0f - zz) * nn + zz * hold;
        const u16 hh = f2bf(hv);
        h0hi[idx] = hh;
        h0lo[idx] = f2bf(hv - bf2f(hh));
      }
    __syncthreads();  // h0 new visible

    // ---------- layer1: ih (A=h0 new, K=128) ----------
#pragma unroll
    for (int kt = 0; kt < 4; ++kt) {
      short8 Ah[8], Al[8];
#pragma unroll
      for (int nt = 0; nt < 8; ++nt) {
        const int node = nt * 16 + li;
        const int g16 = ((kt * 4 + q) ^ (node & 15)) * 8;
        Ah[nt] = *(const short8*)(h0hi + node * TH_ + g16);
        Al[nt] = *(const short8*)(h0lo + node * TH_ + g16);
      }
#pragma unroll
      for (int g = 0; g < 3; ++g) {
        const int ro = roff[g] + kt * 32 + q * 8;
        const short8 bh = *(const short8*)(wih1h + ro);
        const short8 bl = *(const short8*)(wih1l + ro);
#pragma unroll
        for (int nt = 0; nt < 8; ++nt) {
          f32x4 c;
          if (g == 0)      c = (kt == 0) ? z4 : aR[nt];
          else if (g == 1) c = (kt == 0) ? z4 : aZ[nt];
          else             c = (kt == 0) ? z4 : aNI[nt];
          c = mfma3(Ah[nt], Al[nt], bh, bl, c);
          if (g == 0) aR[nt] = c; else if (g == 1) aZ[nt] = c; else aNI[nt] = c;
        }
      }
    }
    // ---------- layer1: hh (A=h1 old, K=128) ----------
#pragma unroll
    for (int kt = 0; kt < 4; ++kt) {
      short8 Ah[8], Al[8];
#pragma unroll
      for (int nt = 0; nt < 8; ++nt) {
        const int node = nt * 16 + li;
        const int g16 = ((kt * 4 + q) ^ (node & 15)) * 8;
        Ah[nt] = *(const short8*)(h1hi + node * TH_ + g16);
        Al[nt] = *(const short8*)(h1lo + node * TH_ + g16);
      }
#pragma unroll
      for (int g = 0; g < 3; ++g) {
        const int ro = roff[g] + kt * 32 + q * 8;
        const short8 bh = *(const short8*)(whh1h + ro);
        const short8 bl = *(const short8*)(whh1l + ro);
#pragma unroll
        for (int nt = 0; nt < 8; ++nt) {
          f32x4 c;
          if (g == 0)      c = aR[nt];
          else if (g == 1) c = aZ[nt];
          else             c = (kt == 0) ? z4 : aNH[nt];
          c = mfma3(Ah[nt], Al[nt], bh, bl, c);
          if (g == 0) aR[nt] = c; else if (g == 1) aZ[nt] = c; else aNH[nt] = c;
        }
      }
    }
    __syncthreads();  // all h0/h1 reads done

    // ---------- gates layer1 -> h1 planes ----------
#pragma unroll
    for (int nt = 0; nt < 8; ++nt)
#pragma unroll
      for (int r = 0; r < 4; ++r) {
        const int node = nt * 16 + q * 4 + r;
        const int idx = node * TH_ + (((unit >> 3) ^ (node & 15)) << 3) + (unit & 7);
        const float hold = bf2f(h1hi[idx]) + bf2f(h1lo[idx]);
        const float rr = sigm_(aR[nt][r] + BR1);
        const float zz = sigm_(aZ[nt][r] + BZ1);
        const float nn = tanh_(aNI[nt][r] + BNI1 + rr * (aNH[nt][r] + BNH1));
        const float hv = (1.0f - zz) * nn + zz * hold;
        const u16 hh = f2bf(hv);
        h1hi[idx] = hh;
        h1lo[idx] = f2bf(hv - bf2f(hh));
      }
    __syncthreads();
  }

  // ---------- LayerNorm(h1) -> temb ----------
  const int n = tid >> 2, qq = tid & 3;
  float vr[32];
  float s = 0.0f;
#pragma unroll
  for (int g8 = 0; g8 < 4; ++g8) {
    const int k0 = qq * 32 + g8 * 8;
    const int g16 = (((k0 >> 3) ^ (n & 15))) * 8;
    const short8 hv = *(const short8*)(h1hi + n * TH_ + g16);
    const short8 lv = *(const short8*)(h1lo + n * TH_ + g16);
#pragma unroll
    for (int j = 0; j < 8; ++j) {
      const float f = bf2f((u16)hv[j]) + bf2f((u16)lv[j]);
      vr[g8 * 8 + j] = f;
      s += f;
    }
  }
  s += __shfl_xor(s, 1, 64); s += __shfl_xor(s, 2, 64);
  const float mu = s * (1.0f / TH_);
  float s2 = 0.0f;
#pragma unroll
  for (int k = 0; k < 32; ++k) { const float d = vr[k] - mu; s2 += d * d; }
  s2 += __shfl_xor(s2, 1, 64); s2 += __shfl_xor(s2, 2, 64);
  const float inv = rsqrtf(s2 * (1.0f / TH_) + 1e-5f);
  float* to = temb + (size_t)(mbase + n) * TH_ + qq * 32;
#pragma unroll
  for (int k = 0; k < 32; ++k)
    to[k] = (vr[k] - mu) * inv * ln1g[qq * 32 + k] + ln1b[qq * 32 + k];
}

// ---------------------------------------------------------------------------
// xp = temb @ gat_W -> [M][64]; a_src/a_dst -> [M][4]
// ---------------------------------------------------------------------------
__global__ __launch_bounds__(256)
void gat_xp_kernel(const float* __restrict__ temb, const float* __restrict__ gatW,
                   const float* __restrict__ attS, const float* __restrict__ attD,
                   float* __restrict__ xp, float* __restrict__ asrc, float* __restrict__ adst)
{
  __shared__ float ts[64][TH_ + 4];
  __shared__ float4 ws4[TH_][16];
  __shared__ float sa[64], sd[64];

  const int tid = threadIdx.x;
  const int mbase = blockIdx.x * 64;

  for (int i = tid; i < 64 * TH_; i += 256) {
    const int n = i >> 7, k = i & 127;
    ts[n][k] = temb[(size_t)mbase * TH_ + i];
  }
  for (int i = tid; i < TH_ * 16; i += 256)
    ((float4*)ws4)[i] = ((const float4*)gatW)[i];
  if (tid < 64) { sa[tid] = attS[tid]; sd[tid] = attD[tid]; }
  __syncthreads();

  const int nl = tid >> 2;
  const int q  = tid & 3;
  float4 acc[4];
#pragma unroll
  for (int i = 0; i < 4; ++i) acc[i] = make_float4(0.f, 0.f, 0.f, 0.f);

  for (int k = 0; k < TH_; ++k) {
    const float tv = ts[nl][k];
#pragma unroll
    for (int c0 = 0; c0 < 4; ++c0) {
      const float4 wv = ws4[k][q * 4 + c0];
      acc[c0].x += tv * wv.x; acc[c0].y += tv * wv.y;
      acc[c0].z += tv * wv.z; acc[c0].w += tv * wv.w;
    }
  }

  float as = 0.0f, ad = 0.0f;
#pragma unroll
  for (int c0 = 0; c0 < 4; ++c0) {
    const int base = q * 16 + c0 * 4;
    as += acc[c0].x * sa[base + 0] + acc[c0].y * sa[base + 1] +
          acc[c0].z * sa[base + 2] + acc[c0].w * sa[base + 3];
    ad += acc[c0].x * sd[base + 0] + acc[c0].y * sd[base + 1] +
          acc[c0].z * sd[base + 2] + acc[c0].w * sd[base + 3];
  }

  const int m = mbase + nl;
  asrc[m * 4 + q] = as;
  adst[m * 4 + q] = ad;
  float4* xpo = (float4*)&xp[(size_t)m * 64 + q * 16];
#pragma unroll
  for (int c0 = 0; c0 < 4; ++c0) xpo[c0] = acc[c0];
}

// ---------------------------------------------------------------------------
// CSR build on the BASE graph (shared by all 16 batch copies)
// ---------------------------------------------------------------------------
__global__ void hist_kernel(const int* __restrict__ ei, const int EB, int* __restrict__ cnt)
{
  const int e = blockIdx.x * 256 + threadIdx.x;
  if (e < EB) atomicAdd(&cnt[ei[EB + e]], 1);
}

__global__ void scan_kernel(const int* __restrict__ cnt, int* __restrict__ offs,
                            int* __restrict__ cursor)
{
  __shared__ int part[256];
  const int tid = threadIdx.x;
  const int c0 = tid * 8;
  int loc[8];
  int s = 0;
#pragma unroll
  for (int j = 0; j < 8; ++j) {
    const int idx = c0 + j;
    const int v = (idx < N_) ? cnt[idx] : 0;
    loc[j] = s; s += v;
  }
  part[tid] = s;
  __syncthreads();
  for (int o = 1; o < 256; o <<= 1) {
    const int v = (tid >= o) ? part[tid - o] : 0;
    __syncthreads();
    part[tid] += v;
    __syncthreads();
  }
  const int base = (tid > 0) ? part[tid - 1] : 0;
#pragma unroll
  for (int j = 0; j < 8; ++j) {
    const int idx = c0 + j;
    if (idx < N_) { offs[idx] = base + loc[j]; cursor[idx] = base + loc[j]; }
  }
  if (tid == 255) offs[N_] = part[255];
}

__global__ void fill_kernel(const int* __restrict__ ei, const int EB,
                            int* __restrict__ cursor, int* __restrict__ ssrc)
{
  const int e = blockIdx.x * 256 + threadIdx.x;
  if (e < EB) {
    const int d = ei[EB + e];
    const int p = atomicAdd(&cursor[d], 1);
    ssrc[p] = ei[e];
  }
}

// ---------------------------------------------------------------------------
// Per-node gather: softmax-weighted aggregate + LN + MLP head -> out[m]
// one 64-lane wave per node (lane = channel), 4 nodes per block
// ---------------------------------------------------------------------------
__global__ __launch_bounds__(256)
void gather_kernel(const int* __restrict__ offs, const int* __restrict__ ssrc,
                   const float* __restrict__ asrc, const float* __restrict__ adst,
                   const float* __restrict__ xp,
                   const float* __restrict__ gatb,
                   const float* __restrict__ ln2g, const float* __restrict__ ln2b,
                   const float* __restrict__ W1, const float* __restrict__ b1,
                   const float* __restrict__ W2, const float* __restrict__ b2,
                   float* __restrict__ out)
{
  __shared__ float sW1[SH_ * 32];
  __shared__ float sb1[32], sW2[32];
  __shared__ float ssemb[4][SH_ + 1];

  const int tid = threadIdx.x;
  for (int i = tid; i < SH_ * 32; i += 256) sW1[i] = W1[i];
  if (tid < 32) { sb1[tid] = b1[tid]; sW2[tid] = W2[tid]; }
  __syncthreads();

  const int lane = tid & 63, grp = tid >> 6;
  const int m = blockIdx.x * 4 + grp;
  const int b = m / N_;
  const int n = m - b * N_;
  const int h = lane >> 4;

  const float adv = adst[m * 4 + h];
  const int o0 = offs[n], o1 = offs[n + 1];
  float accn = 0.0f, accd = 0.0f;
  for (int j = o0; j < o1; ++j) {
    const int s = ssrc[j] + b * N_;
    const float a = asrc[s * 4 + h];
    const float ex = __expf(leaky_(a + adv));
    accn += ex * xp[(size_t)s * 64 + lane];
    accd += ex;
  }
  {  // self loop
    const float a = asrc[m * 4 + h];
    const float ex = __expf(leaky_(a + adv));
    accn += ex * xp[(size_t)m * 64 + lane];
    accd += ex;
  }

  const float v = accn / accd + gatb[lane];
  float s1 = v;
#pragma unroll
  for (int o = 32; o >= 1; o >>= 1) s1 += __shfl_xor(s1, o, 64);
  const float mu = s1 * (1.0f / 64.0f);
  const float d0 = v - mu;
  float s2 = d0 * d0;
#pragma unroll
  for (int o = 32; o >= 1; o >>= 1) s2 += __shfl_xor(s2, o, 64);
  const float var = s2 * (1.0f / 64.0f);
  float sem = d0 * rsqrtf(var + 1e-5f) * ln2g[lane] + ln2b[lane];
  sem = leaky_(sem);

  ssemb[grp][lane] = sem;
  __syncthreads();

  float contrib = 0.0f;
  if (lane < 32) {
    float acc = sb1[lane];
    for (int c = 0; c < SH_; ++c) acc += ssemb[grp][c] * sW1[c * 32 + lane];
    acc = leaky_(acc);
    contrib = acc * sW2[lane];
  }
#pragma unroll
  for (int o = 32; o >= 1; o >>= 1) contrib += __shfl_xor(contrib, o, 64);
  if (lane == 0) out[m] = contrib + b2[0];
}

// ---------------------------------------------------------------------------
extern "C" void kernel_launch(void* const* d_in, const int* in_sizes, int n_in,
                              void* d_out, int out_size, void* d_ws, size_t ws_size,
                              hipStream_t stream)
{
  const float* x    = (const float*)d_in[0];
  const int*   ei   = (const int*)d_in[1];
  const float* Wih0 = (const float*)d_in[2];
  const float* Whh0 = (const float*)d_in[3];
  const float* bih0 = (const float*)d_in[4];
  const float* bhh0 = (const float*)d_in[5];
  const float* Wih1 = (const float*)d_in[6];
  const float* Whh1 = (const float*)d_in[7];
  const float* bih1 = (const float*)d_in[8];
  const float* bhh1 = (const float*)d_in[9];
  const float* ln1g = (const float*)d_in[10];
  const float* ln1b = (const float*)d_in[11];
  const float* gatW = (const float*)d_in[12];
  const float* attS = (const float*)d_in[13];
  const float* attD = (const float*)d_in[14];
  const float* gatb = (const float*)d_in[15];
  const float* ln2g = (const float*)d_in[16];
  const float* ln2b = (const float*)d_in[17];
  const float* W1   = (const float*)d_in[18];
  const float* b1   = (const float*)d_in[19];
  const float* W2   = (const float*)d_in[20];
  const float* b2   = (const float*)d_in[21];
  float* out = (float*)d_out;

  const int EB = in_sizes[1] / 2;

  float* ws = (float*)d_ws;
  float* temb = ws;                                  // M*128
  float* xp   = temb + (size_t)M_ * TH_;             // M*64
  float* asrc = xp + (size_t)M_ * 64;                // M*4
  float* adst = asrc + (size_t)M_ * 4;               // M*4
  u16*   wsp  = (u16*)(adst + (size_t)M_ * 4);       // split weights (bf16 hi/lo)
  int*   cnt    = (int*)(wsp + 2 * S0_ + 6 * S1_);   // N_
  int*   offs   = cnt + N_;                          // N_+1
  int*   cursor = offs + N_ + 1;                     // N_
  int*   ssrc   = cursor + N_;                       // EB

  const u16* wih0h = wsp;
  const u16* wih0l = wsp + S0_;
  const u16* whh0h = wsp + 2 * S0_;
  const u16* whh0l = whh0h + S1_;
  const u16* wih1h = whh0l + S1_;
  const u16* wih1l = wih1h + S1_;
  const u16* whh1h = wih1l + S1_;
  const u16* whh1l = whh1h + S1_;

  const int NSPLIT = S0_ + 3 * S1_;
  splitw_kernel<<<(NSPLIT + 255) / 256, 256, 0, stream>>>(Wih0, Whh0, Wih1, Whh1, wsp);

  hipMemsetAsync(cnt, 0, N_ * sizeof(int), stream);
  hist_kernel<<<(EB + 255) / 256, 256, 0, stream>>>(ei, EB, cnt);
  scan_kernel<<<1, 256, 0, stream>>>(cnt, offs, cursor);
  fill_kernel<<<(EB + 255) / 256, 256, 0, stream>>>(ei, EB, cursor, ssrc);

  gru_mfma_kernel<<<M_ / NPB, 512, 0, stream>>>(
      x, wih0h, wih0l, whh0h, whh0l, wih1h, wih1l, whh1h, whh1l,
      bih0, bhh0, bih1, bhh1, ln1g, ln1b, temb);

  gat_xp_kernel<<<M_ / 64, 256, 0, stream>>>(temb, gatW, attS, attD, xp, asrc, adst);

  gather_kernel<<<M_ / 4, 256, 0, stream>>>(offs, ssrc, asrc, adst, xp,
                                            gatb, ln2g, ln2b, W1, b1, W2, b2, out);
}